// Round 13
// baseline (249.877 us; speedup 1.0000x reference)
//
#include <hip/hip_runtime.h>

#define N_NODES 100000
#define N_EDGES 1600000
#define D 128
#define NB 512        // buckets; b = r*512/100000, ~195.3 rows, mean 3125 edges
#define BCAP 3584     // mean 3125 + 8 sigma rounded up
#define BSTRIDE 16    // bucket counter padding (64 B)
#define CHUNK 3200    // edges per scatter block; 500 blocks x 3200 = 1.6M exactly
#define NSCAT 500
#define NCAST 521     // cast blocks; grid NSCAT+NCAST = 1021 <= 1024 co-resident
#define HCAP 1792     // half-bucket capacity

typedef __attribute__((ext_vector_type(8))) short  short8;   // 8 bf16 (4 VGPR) MFMA A/B frag
typedef __attribute__((ext_vector_type(4))) float  floatx4;  // MFMA C/D frag

__device__ __forceinline__ ushort f2bf(float f) {   // fp32 -> bf16 RNE
    unsigned u = __float_as_uint(f);
    u += 0x7FFF + ((u >> 16) & 1);
    return (ushort)(u >> 16);
}
__device__ __forceinline__ float bf2f(ushort s) {
    return __uint_as_float((unsigned)s << 16);
}
__device__ __forceinline__ int bucket_of(int r)  { return (int)(((unsigned)r << 9) / 100000u); }
__device__ __forceinline__ int row_start(int b)  { return (b * 100000 + 511) >> 9; }

// ---------------- K1: cast x->bf16 + W->swizzled bf16 (blocks >= NSCAT) + scatter ----
__global__ __launch_bounds__(256, 4) void cast_and_scatter(const float* __restrict__ x,
                                                           const float* __restrict__ w,
                                                           ushort* __restrict__ xb,
                                                           ushort* __restrict__ wtg,
                                                           const int* __restrict__ erow,
                                                           const int* __restrict__ ecol,
                                                           const float* __restrict__ eval,
                                                           int* __restrict__ bcnt,
                                                           int2* __restrict__ bkt) {
    __shared__ int2  stage[CHUNK];     // 25600 B
    __shared__ int   sA[NB], sB[NB], lcur[NB], gbase[NB];
    __shared__ short sbuck[CHUNK];     //  6400 B   (total 40192 B -> 4 blocks/CU)
    const int t = threadIdx.x;

    if (blockIdx.x >= NSCAT) {
        const int bid = blockIdx.x - NSCAT;
        if (bid == 0) {
            // ---- stage W into swizzled bf16 global layout (R10-proven mapping) ----
            const float4* w4 = (const float4*)w;   // w4[k*32 + ncol4]
            const int kb    = t & 7;
            const int ncol4 = t >> 3;              // 0..31
            const int nc    = ncol4 << 2;
            for (int it = 0; it < 16; ++it) {
                const int k = kb + it * 8;
                const float4 v = w4[k * 32 + ncol4];
                const int c = k >> 3, kc = k & 7;
#pragma unroll
                for (int d = 0; d < 4; ++d) {
                    const float val = (d == 0) ? v.x : (d == 1) ? v.y : (d == 2) ? v.z : v.w;
                    const int nn = nc + d;
                    wtg[(nn << 7) | (((c ^ (nn & 15)) & 15) << 3) | kc] = f2bf(val);
                }
            }
        }
        // ---- cast: x (fp32) -> xb (bf16), fully coalesced, grid-stride ----
        const int gid = bid * 256 + t;
        const float4* x4 = (const float4*)x;           // 3,200,000 float4
        for (int i = gid; i < (N_NODES * D / 4); i += NCAST * 256) {
            const float4 v = x4[i];
            ushort4 o;
            o.x = f2bf(v.x); o.y = f2bf(v.y); o.z = f2bf(v.z); o.w = f2bf(v.w);
            ((ushort4*)xb)[i] = o;
        }
        return;
    }

    // ---- bucket_scatter: LDS counting-sort by bucket (proven) ----
    const int e0 = blockIdx.x * CHUNK;

    sA[t] = 0; sA[t + 256] = 0;
    __syncthreads();

    for (int i = t; i < CHUNK; i += 256) {
        atomicAdd(&sA[bucket_of(erow[e0 + i])], 1);
    }
    __syncthreads();

    int cur = 0;
    int* bufs[2] = {sA, sB};
#pragma unroll
    for (int o = 1; o < 512; o <<= 1) {
        const int* src = bufs[cur];
        int*       dst = bufs[cur ^ 1];
        const int i0 = t, i1 = t + 256;
        dst[i0] = src[i0] + ((i0 >= o) ? src[i0 - o] : 0);
        dst[i1] = src[i1] + ((i1 >= o) ? src[i1 - o] : 0);
        cur ^= 1;
        __syncthreads();
    }
    {
        const int* incl = bufs[cur];
        int*       excl = bufs[cur ^ 1];
        excl[t]       = (t == 0) ? 0 : incl[t - 1];
        excl[t + 256] = incl[t + 255];
    }
    __syncthreads();
    int* L = bufs[cur ^ 1];   // exclusive bases; L[511] valid

    for (int b = t; b < NB; b += 256) {
        lcur[b] = L[b];
        const int cnt = ((b == NB - 1) ? CHUNK : L[b + 1]) - L[b];
        gbase[b] = (cnt > 0) ? atomicAdd(&bcnt[b * BSTRIDE], cnt) : 0;
    }
    __syncthreads();

    for (int i = t; i < CHUNK; i += 256) {
        const int   r = erow[e0 + i];
        const int   c = ecol[e0 + i];
        const float v = eval[e0 + i];
        const int   b = bucket_of(r);
        const int  rl = r - row_start(b);
        const int pos = atomicAdd(&lcur[b], 1);
        stage[pos] = make_int2((rl << 17) | c, __float_as_int(v));
        sbuck[pos] = (short)b;
    }
    __syncthreads();

    for (int i = t; i < CHUNK; i += 256) {
        const int b   = sbuck[i];
        const int dst = gbase[b] + (i - L[b]);
        if (dst < BCAP) bkt[(size_t)b * BCAP + dst] = stage[i];
    }
}

// ---------------- K2: gather from xb + MFMA epilogue, coalesced C store via LDS repack ----
// R13 change vs R12 (counter-diagnosed): R12's scalar column-strided out stores
// caused write-allocate RMW (FETCH +74 MB, WRITE +69 MB). Now C is repacked
// through the reused wave-private gbuf (as 16x64 fp32, two column-half passes,
// XOR-chunk swizzle -- R9's proven ct pattern) -> 256 B contiguous float4
// stores, full lines, no RMW. LDS unchanged (reuse) -> stays 4 blocks/CU.
__global__ __launch_bounds__(256, 4) void gather_gemm(const int* __restrict__ bcnt,
                                                      const int2* __restrict__ bkt,
                                                      const ushort* __restrict__ xb,
                                                      const ushort* __restrict__ wtg,
                                                      float* __restrict__ out) {
    __shared__ int2   lcsr[HCAP];        // 14336 B
    __shared__ int    sA[256], sB[256], lcur[256];   // 3072 B
    __shared__ ushort gbuf[4][16 * 128]; // 16384 B  per-wave A staging / C repack (reused)
    const int bg = blockIdx.x;           // 0..2*NB-1
    const int b  = bg >> 1;
    const int h  = bg & 1;
    const int t  = threadIdx.x;
    const int n  = min(bcnt[b * BSTRIDE], BCAP);
    const int r0    = row_start(b);
    const int nrows = row_start(b + 1) - r0;
    const int mid   = (nrows + 1) >> 1;
    const int lo    = h ? mid : 0;
    const int hi    = h ? nrows : mid;
    const int nloc  = hi - lo;

    const int2* src = bkt + (size_t)b * BCAP;
    sA[t] = 0;
    __syncthreads();

    // CSR build (proven): histogram -> scan -> place
    for (int i = t; i < n; i += 256) {
        const int rl = (int)(((unsigned)src[i].x) >> 17);
        if (rl >= lo && rl < hi) atomicAdd(&sA[rl - lo], 1);
    }
    __syncthreads();

    int cur = 0;
    int* bufs[2] = {sA, sB};
#pragma unroll
    for (int o = 1; o < 256; o <<= 1) {
        const int* s = bufs[cur];
        int*       d = bufs[cur ^ 1];
        d[t] = s[t] + ((t >= o) ? s[t - o] : 0);
        cur ^= 1;
        __syncthreads();
    }
    lcur[t] = (t == 0) ? 0 : bufs[cur][t - 1];
    __syncthreads();

    for (int i = t; i < n; i += 256) {
        const int2 e = src[i];
        const int rl = (int)(((unsigned)e.x) >> 17);
        if (rl >= lo && rl < hi) {
            const int pos = atomicAdd(&lcur[rl - lo], 1);
            if (pos < HCAP) lcsr[pos] = make_int2(e.x & 0x1FFFF, e.y);
        }
    }
    __syncthreads();

    // ---- gather + per-wave MFMA epilogue ----
    const int wv  = t >> 6;
    const int ln64 = t & 63;
    const int qq  = ln64 >> 4;        // quarter in wave (gather row / MFMA k-offset)
    const int m16 = ln64 & 15;        // col-chunk in gather / A-row & B-col in MFMA
    const int lc  = m16 << 3;         // 8 cols per lane
    ushort* gb = gbuf[wv];
    const int base_row = wv * 4;
    const int IT = (nloc > base_row) ? ((nloc - base_row + 15) >> 4) : 0;  // wave-uniform
    const int MBN = (IT + 3) >> 2;

    for (int mb = 0; mb < MBN; ++mb) {
#pragma unroll
        for (int j = 0; j < 4; ++j) {
            const int it = mb * 4 + j;
            const int ln = base_row + qq + 16 * it;

            float acc[8] = {0, 0, 0, 0, 0, 0, 0, 0};
            if (ln < nloc) {
                int start = (ln == 0) ? 0 : lcur[ln - 1];
                int end   = lcur[ln];
                start = min(start, HCAP);
                end   = min(end, HCAP);

                for (int jj = start; jj < end; jj += 4) {
                    const int jb = jj + 1, jc = jj + 2, jd = jj + 3;
                    const int2 e0 = lcsr[jj];
                    const int2 e1 = lcsr[min(jb, end - 1)];
                    const int2 e2 = lcsr[min(jc, end - 1)];
                    const int2 e3 = lcsr[min(jd, end - 1)];
                    const short8 m0 = *(const short8*)&xb[(size_t)e0.x * D + lc];
                    const short8 m1 = *(const short8*)&xb[(size_t)e1.x * D + lc];
                    const short8 m2 = *(const short8*)&xb[(size_t)e2.x * D + lc];
                    const short8 m3 = *(const short8*)&xb[(size_t)e3.x * D + lc];
                    const float v0 = __int_as_float(e0.y);
                    const float v1 = (jb < end) ? __int_as_float(e1.y) : 0.f;
                    const float v2 = (jc < end) ? __int_as_float(e2.y) : 0.f;
                    const float v3 = (jd < end) ? __int_as_float(e3.y) : 0.f;
#pragma unroll
                    for (int i = 0; i < 8; ++i) {
                        acc[i] += v0 * bf2f((ushort)m0[i]);
                        acc[i] += v1 * bf2f((ushort)m1[i]);
                        acc[i] += v2 * bf2f((ushort)m2[i]);
                        acc[i] += v3 * bf2f((ushort)m3[i]);
                    }
                }
            }
            // write bf16 G-row to slot s (XOR-chunk swizzle, 16 B per lane)
            const int s    = (j << 2) | qq;
            const int phys = m16 ^ (s & 7);
            short8 og;
#pragma unroll
            for (int i = 0; i < 8; ++i) og[i] = (short)f2bf(acc[i]);
            *(short8*)&gb[s * 128 + (phys << 3)] = og;
        }

        // MFMA: A = gbuf rows (lane m16 = slot row, qq = k-offset), B = wtg (global, L2)
        short8 afr[4];
#pragma unroll
        for (int k2 = 0; k2 < 4; ++k2) {
            const int ph = (((k2 << 2) | qq) ^ (m16 & 7));
            afr[k2] = *(const short8*)&gb[m16 * 128 + (ph << 3)];
        }
        floatx4 c8[8];
#pragma unroll
        for (int tt = 0; tt < 8; ++tt) c8[tt] = (floatx4){0.f, 0.f, 0.f, 0.f};
#pragma unroll
        for (int k2 = 0; k2 < 4; ++k2) {
#pragma unroll
            for (int tt = 0; tt < 8; ++tt) {
                const int bn = tt * 16 + m16;
                const int cc = (((k2 << 2) + qq) ^ m16) & 15;
                const short8 bb = *(const short8*)&wtg[(bn << 7) | (cc << 3)];
                c8[tt] = __builtin_amdgcn_mfma_f32_16x16x32_bf16(afr[k2], bb, c8[tt], 0, 0, 0);
            }
        }

        // ---- C repack through reused gbuf (as 16x64 fp32) -> coalesced 64 B/lane stores ----
        // Same-wave DS ordering + c8 data dependency guarantee the afr reads above
        // complete before these writes overwrite gbuf.
        float* gf = (float*)gb;   // 16 x 64 fp32 (4 KB), wave-private
#pragma unroll
        for (int p = 0; p < 2; ++p) {
#pragma unroll
            for (int tt2 = 0; tt2 < 4; ++tt2) {
#pragma unroll
                for (int r = 0; r < 4; ++r) {
                    const int row  = (qq << 2) | r;            // C row = slot index
                    const int slot = (tt2 ^ r ^ qq) & 3;       // XOR chunk swizzle
                    gf[row * 64 + slot * 16 + m16] = fmaxf(c8[p * 4 + tt2][r], 0.f);
                }
            }
            const int rl   = ln64 >> 2;          // 0..15 slot row
            const int ch   = ln64 & 3;           // 64 B chunk within 256 B half-row
            const int slot = (ch ^ (rl & 3) ^ (rl >> 2)) & 3;
            const int ln2  = base_row + (rl & 3) + 16 * (mb * 4 + (rl >> 2));
            if (ln2 < nloc) {
                const float* srcp = &gf[rl * 64 + slot * 16];
                float* dstp = out + (size_t)(r0 + lo + ln2) * D + p * 64 + ch * 16;
                ((float4*)dstp)[0] = ((const float4*)srcp)[0];
                ((float4*)dstp)[1] = ((const float4*)srcp)[1];
                ((float4*)dstp)[2] = ((const float4*)srcp)[2];
                ((float4*)dstp)[3] = ((const float4*)srcp)[3];
            }
        }
    }
}

extern "C" void kernel_launch(void* const* d_in, const int* in_sizes, int n_in,
                              void* d_out, int out_size, void* d_ws, size_t ws_size,
                              hipStream_t stream) {
    const float* x    = (const float*)d_in[0];
    const float* w    = (const float*)d_in[1];
    const int*   erow = (const int*)d_in[2];
    const int*   ecol = (const int*)d_in[3];
    const float* eval = (const float*)d_in[4];
    float*       out  = (float*)d_out;

    // workspace layout (16 B aligned):
    char*   ws_base = (char*)d_ws;
    ushort* xb   = (ushort*)ws_base;                 // 25,600,000 B  bf16 x
    int*    bcnt = (int*)(ws_base + 25600000);       //     32,768 B  (512 * 64 B)
    int2*   bkt  = (int2*)(ws_base + 25632768);      // 14,680,064 B  (512 * 3584 * 8)
    ushort* wtg  = (ushort*)(ws_base + 40312832);    //     32,768 B  swizzled bf16 W
    // total ~40.35 MB

    (void)hipMemsetAsync(bcnt, 0, 32768, stream);

    cast_and_scatter<<<NSCAT + NCAST, 256, 0, stream>>>(x, w, xb, wtg, erow, ecol, eval, bcnt, bkt);
    gather_gemm<<<NB * 2, 256, 0, stream>>>(bcnt, bkt, xb, wtg, out);
}

// Round 14
// 211.154 us; speedup vs baseline: 1.1834x; 1.1834x over previous
//
#include <hip/hip_runtime.h>

#define N_NODES 100000
#define N_EDGES 1600000
#define D 128
#define NB 512        // buckets; b = r*512/100000, ~195.3 rows, mean 3125 edges
#define BCAP 3584     // mean 3125 + 8 sigma rounded up
#define BSTRIDE 16    // bucket counter padding (64 B)
#define CHUNK 3200    // edges per scatter block; 500 blocks x 3200 = 1.6M exactly
#define NSCAT 500
#define NGEMMB 521    // persistent gemm blocks; 1563 = 3 x 521 -> exactly 3 tiles each
#define NTILES 1563   // ceil(100000/64) 64-row tiles
#define HCAP 1792     // half-bucket capacity

typedef __attribute__((ext_vector_type(8))) short  short8;   // 8 bf16 (4 VGPR) MFMA A/B frag
typedef __attribute__((ext_vector_type(4))) float  floatx4;  // MFMA C/D frag

__device__ __forceinline__ ushort f2bf(float f) {   // fp32 -> bf16 RNE
    unsigned u = __float_as_uint(f);
    u += 0x7FFF + ((u >> 16) & 1);
    return (ushort)(u >> 16);
}
__device__ __forceinline__ float bf2f(ushort s) {
    return __uint_as_float((unsigned)s << 16);
}
__device__ __forceinline__ int bucket_of(int r)  { return (int)(((unsigned)r << 9) / 100000u); }
__device__ __forceinline__ int row_start(int b)  { return (b * 100000 + 511) >> 9; }

// ---------------- fused: bucket_scatter (blocks 0..499) + persistent gemm (500..1020) ----
// R14 = R9 (best verified, 214.1 us) + R10's wt-staging thread remap. R8's
// counters showed deterministic SQ_LDS_BANK_CONFLICT=4.58M from the old map
// (32 half-wave lanes writing 1024 B apart = 32-way same-bank); the remap
// (k-major within 8-lane groups, same final layout) is <=4-way. Everything
// else byte-identical to R9.
union SMem {
    struct {                       // scatter branch: 40192 B
        int2  stage[CHUNK];        // 25600
        int   sA[NB];              //  2048
        int   sB[NB];              //  2048
        int   lcur[NB];            //  2048
        int   gbase[NB];           //  2048
        short sbuck[CHUNK];        //  6400
    } sc;
    struct {                       // gemm branch: 40960 B
        ushort wt[128 * 128];      // 32768  B-matrix, bank-swizzled
        ushort ct[4][16 * 64];     //  8192  per-wave half-row repack, XOR-swizzled
    } ge;
};

__global__ __launch_bounds__(256, 4) void gemm_and_scatter(const float* __restrict__ x,
                                                           const float* __restrict__ w,
                                                           ushort* __restrict__ xwb,
                                                           const int* __restrict__ erow,
                                                           const int* __restrict__ ecol,
                                                           const float* __restrict__ eval,
                                                           int* __restrict__ bcnt,
                                                           int2* __restrict__ bkt) {
    __shared__ SMem sm;
    const int t = threadIdx.x;

    if (blockIdx.x >= NSCAT) {
        // ================= persistent GEMM: xw = bf16(x @ w) =================
        const int bid  = blockIdx.x - NSCAT;
        ushort* wt = sm.ge.wt;
        const int wv   = t >> 6;
        const int lane = t & 63;
        const int m    = lane & 15;
        const int q    = lane >> 4;

        {
            // R10 remap: lanes t&7 cover k (bank-adjacent kc), t>>3 covers ncol4
            const float4* w4 = (const float4*)w;   // w4[k*32 + ncol4]
            const int kb    = t & 7;
            const int ncol4 = t >> 3;              // 0..31
            const int nc    = ncol4 << 2;
            for (int it = 0; it < 16; ++it) {
                const int k = kb + it * 8;
                const float4 v = w4[k * 32 + ncol4];
                const int c = k >> 3, kc = k & 7;
#pragma unroll
                for (int d = 0; d < 4; ++d) {
                    const float val = (d == 0) ? v.x : (d == 1) ? v.y : (d == 2) ? v.z : v.w;
                    const int nn = nc + d;
                    wt[(nn << 7) | (((c ^ (nn & 15)) & 15) << 3) | kc] = f2bf(val);
                }
            }
        }
        __syncthreads();   // the ONLY barrier; everything below is wave-local

        float4 xa[8];
        {
            const int rb0 = bid * 64 + wv * 16;
            const float* xr = x + (size_t)min(rb0 + m, N_NODES - 1) * D + q * 8;
#pragma unroll
            for (int k2 = 0; k2 < 4; ++k2) {
                xa[k2 * 2 + 0] = *(const float4*)(xr + k2 * 32);
                xa[k2 * 2 + 1] = *(const float4*)(xr + k2 * 32 + 4);
            }
        }

        for (int tb = bid; tb < NTILES; tb += NGEMMB) {
            const int rbase = tb * 64 + wv * 16;

            short8 afr[4];
#pragma unroll
            for (int k2 = 0; k2 < 4; ++k2) {
                const float4 a0 = xa[k2 * 2 + 0];
                const float4 a1 = xa[k2 * 2 + 1];
                short8 a;
                a[0] = (short)f2bf(a0.x); a[1] = (short)f2bf(a0.y);
                a[2] = (short)f2bf(a0.z); a[3] = (short)f2bf(a0.w);
                a[4] = (short)f2bf(a1.x); a[5] = (short)f2bf(a1.y);
                a[6] = (short)f2bf(a1.z); a[7] = (short)f2bf(a1.w);
                afr[k2] = a;
            }

            const int tnext = tb + NGEMMB;
            if (tnext < NTILES) {
                const int rbn = tnext * 64 + wv * 16;
                const float* xr = x + (size_t)min(rbn + m, N_NODES - 1) * D + q * 8;
#pragma unroll
                for (int k2 = 0; k2 < 4; ++k2) {
                    xa[k2 * 2 + 0] = *(const float4*)(xr + k2 * 32);
                    xa[k2 * 2 + 1] = *(const float4*)(xr + k2 * 32 + 4);
                }
            }

            floatx4 acc[8];
#pragma unroll
            for (int tt = 0; tt < 8; ++tt) acc[tt] = (floatx4){0.f, 0.f, 0.f, 0.f};

#pragma unroll
            for (int k2 = 0; k2 < 4; ++k2) {
#pragma unroll
                for (int tt = 0; tt < 8; ++tt) {
                    const int n  = tt * 16 + m;
                    const int cc = (((k2 << 2) + q) ^ m) & 15;
                    const short8 b = *(const short8*)&wt[(n << 7) | (cc << 3)];
                    acc[tt] = __builtin_amdgcn_mfma_f32_16x16x32_bf16(afr[k2], b, acc[tt], 0, 0, 0);
                }
            }

            // repack C in two column-half passes through 2 KB/wave XOR-swizzled ct
#pragma unroll
            for (int p = 0; p < 2; ++p) {
#pragma unroll
                for (int tt2 = 0; tt2 < 4; ++tt2) {
#pragma unroll
                    for (int r = 0; r < 4; ++r) {
                        const int row  = (q << 2) | r;
                        const int slot = (tt2 ^ r ^ q) & 3;
                        sm.ge.ct[wv][row * 64 + slot * 16 + m] = f2bf(acc[p * 4 + tt2][r]);
                    }
                }
                const int rl   = lane >> 2;          // 0..15 local row
                const int ch   = lane & 3;           // 32 B chunk within the 128 B half-row
                const int slot = (ch ^ (rl & 3) ^ (rl >> 2)) & 3;
                const ushort* srcp = &sm.ge.ct[wv][rl * 64 + slot * 16];
                if (rbase + rl < N_NODES) {
                    ushort* dstp = &xwb[(size_t)(rbase + rl) * D + p * 64 + ch * 16];
                    ((int4*)dstp)[0] = ((const int4*)srcp)[0];
                    ((int4*)dstp)[1] = ((const int4*)srcp)[1];
                }
            }
        }
    } else {
        // ================= bucket_scatter: LDS counting-sort by bucket =================
        const int e0 = blockIdx.x * CHUNK;
        int*   sA    = sm.sc.sA;
        int*   sB    = sm.sc.sB;
        int*   lcur  = sm.sc.lcur;
        int*   gbase = sm.sc.gbase;
        short* sbuck = sm.sc.sbuck;
        int2*  stage = sm.sc.stage;

        sA[t] = 0; sA[t + 256] = 0;
        __syncthreads();

        for (int i = t; i < CHUNK; i += 256) {
            atomicAdd(&sA[bucket_of(erow[e0 + i])], 1);
        }
        __syncthreads();

        int cur = 0;
        int* bufs[2] = {sA, sB};
#pragma unroll
        for (int o = 1; o < 512; o <<= 1) {
            const int* src = bufs[cur];
            int*       dst = bufs[cur ^ 1];
            const int i0 = t, i1 = t + 256;
            dst[i0] = src[i0] + ((i0 >= o) ? src[i0 - o] : 0);
            dst[i1] = src[i1] + ((i1 >= o) ? src[i1 - o] : 0);
            cur ^= 1;
            __syncthreads();
        }
        {
            const int* incl = bufs[cur];
            int*       excl = bufs[cur ^ 1];
            excl[t]       = (t == 0) ? 0 : incl[t - 1];
            excl[t + 256] = incl[t + 255];
        }
        __syncthreads();
        int* L = bufs[cur ^ 1];   // exclusive bases; L[511] valid

        for (int b = t; b < NB; b += 256) {
            lcur[b] = L[b];
            const int cnt = ((b == NB - 1) ? CHUNK : L[b + 1]) - L[b];
            gbase[b] = (cnt > 0) ? atomicAdd(&bcnt[b * BSTRIDE], cnt) : 0;
        }
        __syncthreads();

        for (int i = t; i < CHUNK; i += 256) {
            const int   r = erow[e0 + i];
            const int   c = ecol[e0 + i];
            const float v = eval[e0 + i];
            const int   b = bucket_of(r);
            const int  rl = r - row_start(b);
            const int pos = atomicAdd(&lcur[b], 1);
            stage[pos] = make_int2((rl << 17) | c, __float_as_int(v));
            sbuck[pos] = (short)b;
        }
        __syncthreads();

        for (int i = t; i < CHUNK; i += 256) {
            const int b   = sbuck[i];
            const int dst = gbase[b] + (i - L[b]);
            if (dst < BCAP) bkt[(size_t)b * BCAP + dst] = stage[i];
        }
    }
}

// ---------------- fused CSR-build + gather: TWO blocks per bucket (R9-proven) ----------------
__global__ __launch_bounds__(256, 4) void csr_gather(const int* __restrict__ bcnt,
                                                     const int2* __restrict__ bkt,
                                                     const ushort* __restrict__ xwb,
                                                     float* __restrict__ out) {
    __shared__ int2 lcsr[HCAP];      // 14336 B
    __shared__ int  sA[256], sB[256], lcur[256];
    const int bg = blockIdx.x;       // 0..2*NB-1
    const int b  = bg >> 1;
    const int h  = bg & 1;
    const int t  = threadIdx.x;
    const int n  = min(bcnt[b * BSTRIDE], BCAP);
    const int r0    = row_start(b);
    const int nrows = row_start(b + 1) - r0;
    const int mid   = (nrows + 1) >> 1;
    const int lo    = h ? mid : 0;
    const int hi    = h ? nrows : mid;
    const int nloc  = hi - lo;

    const int2* src = bkt + (size_t)b * BCAP;
    sA[t] = 0;
    __syncthreads();

    for (int i = t; i < n; i += 256) {
        const int rl = (int)(((unsigned)src[i].x) >> 17);
        if (rl >= lo && rl < hi) atomicAdd(&sA[rl - lo], 1);
    }
    __syncthreads();

    int cur = 0;
    int* bufs[2] = {sA, sB};
#pragma unroll
    for (int o = 1; o < 256; o <<= 1) {
        const int* s = bufs[cur];
        int*       d = bufs[cur ^ 1];
        d[t] = s[t] + ((t >= o) ? s[t - o] : 0);
        cur ^= 1;
        __syncthreads();
    }
    lcur[t] = (t == 0) ? 0 : bufs[cur][t - 1];
    __syncthreads();

    for (int i = t; i < n; i += 256) {
        const int2 e = src[i];
        const int rl = (int)(((unsigned)e.x) >> 17);
        if (rl >= lo && rl < hi) {
            const int pos = atomicAdd(&lcur[rl - lo], 1);
            if (pos < HCAP) lcsr[pos] = make_int2(e.x & 0x1FFFF, e.y);
        }
    }
    __syncthreads();

    const int qid = t >> 4;          // quarter-wave id within block, 0..15
    const int lc  = (t & 15) << 3;   // 8 cols per lane

    for (int ln = qid; ln < nloc; ln += 16) {
        int start = (ln == 0) ? 0 : lcur[ln - 1];
        int end   = lcur[ln];
        start = min(start, HCAP);
        end   = min(end, HCAP);

        float acc[8] = {0, 0, 0, 0, 0, 0, 0, 0};

        for (int j = start; j < end; j += 4) {
            const int jb = j + 1, jc = j + 2, jd = j + 3;
            const int2 e0 = lcsr[j];
            const int2 e1 = lcsr[min(jb, end - 1)];
            const int2 e2 = lcsr[min(jc, end - 1)];
            const int2 e3 = lcsr[min(jd, end - 1)];
            const short8 m0 = *(const short8*)&xwb[(size_t)e0.x * D + lc];
            const short8 m1 = *(const short8*)&xwb[(size_t)e1.x * D + lc];
            const short8 m2 = *(const short8*)&xwb[(size_t)e2.x * D + lc];
            const short8 m3 = *(const short8*)&xwb[(size_t)e3.x * D + lc];
            const float v0 = __int_as_float(e0.y);
            const float v1 = (jb < end) ? __int_as_float(e1.y) : 0.f;
            const float v2 = (jc < end) ? __int_as_float(e2.y) : 0.f;
            const float v3 = (jd < end) ? __int_as_float(e3.y) : 0.f;
#pragma unroll
            for (int i = 0; i < 8; ++i) {
                acc[i] += v0 * bf2f((ushort)m0[i]);
                acc[i] += v1 * bf2f((ushort)m1[i]);
                acc[i] += v2 * bf2f((ushort)m2[i]);
                acc[i] += v3 * bf2f((ushort)m3[i]);
            }
        }

        float* o = out + (size_t)(r0 + lo + ln) * D + lc;
        *(float4*)(o + 0) = make_float4(fmaxf(acc[0], 0.f), fmaxf(acc[1], 0.f),
                                        fmaxf(acc[2], 0.f), fmaxf(acc[3], 0.f));
        *(float4*)(o + 4) = make_float4(fmaxf(acc[4], 0.f), fmaxf(acc[5], 0.f),
                                        fmaxf(acc[6], 0.f), fmaxf(acc[7], 0.f));
    }
}

extern "C" void kernel_launch(void* const* d_in, const int* in_sizes, int n_in,
                              void* d_out, int out_size, void* d_ws, size_t ws_size,
                              hipStream_t stream) {
    const float* x    = (const float*)d_in[0];
    const float* w    = (const float*)d_in[1];
    const int*   erow = (const int*)d_in[2];
    const int*   ecol = (const int*)d_in[3];
    const float* eval = (const float*)d_in[4];
    float*       out  = (float*)d_out;

    // workspace layout (16 B aligned):
    char*   ws_base = (char*)d_ws;
    ushort* xwb  = (ushort*)ws_base;                 // 25,600,000 B  bf16 xw
    int*    bcnt = (int*)(ws_base + 25600000);       //     32,768 B  (512 * 64 B)
    int2*   bkt  = (int2*)(ws_base + 25632768);      // 14,680,064 B  (512 * 3584 * 8)
    // total ~40.3 MB

    (void)hipMemsetAsync(bcnt, 0, 32768, stream);

    gemm_and_scatter<<<NSCAT + NGEMMB, 256, 0, stream>>>(x, w, xwb, erow, ecol, eval, bcnt, bkt);
    csr_gather<<<NB * 2, 256, 0, stream>>>(bcnt, bkt, xwb, out);
}